// Round 4
// baseline (798.087 us; speedup 1.0000x reference)
//
#include <hip/hip_runtime.h>

// Fused MLP: x[131072,512] -> (Linear+LN+CELU)x4 -> spectral-norm head -> [131072,1]
// R4: PERSISTENT blocks (grid=256, 8 tiles of 64 rows each) with cross-tile x
// prefetch held in registers; GEMM1 runs barrier-free from a full x-tile staged
// in LDS (buffer shared with h1 - x dead after K-loop); unique-Ng waves read W1
// exactly once per block. Weights pre-packed in MFMA-fragment order (coalesced
// 1KB bursts). GEMM1/2 bf16 MFMA + in-register fp32 LayerNorm; GEMM3
// split-precision bf16; layer4+head fp32.

typedef unsigned short u16;
typedef unsigned int   u32;
typedef __bf16  bf16x8 __attribute__((ext_vector_type(8)));
typedef float   f32x16 __attribute__((ext_vector_type(16)));

__device__ __forceinline__ u16 f2bf(float f) {           // RTN-even f32->bf16
    u32 x = __builtin_bit_cast(u32, f);
    x += 0x7FFFu + ((x >> 16) & 1u);
    return (u16)(x >> 16);
}
__device__ __forceinline__ float bfval(u16 h) { return __builtin_bit_cast(float, (u32)h << 16); }
__device__ __forceinline__ u32 pack2(float a, float b) { return (u32)f2bf(a) | ((u32)f2bf(b) << 16); }
__device__ __forceinline__ float celu1(float x) { return x > 0.f ? x : __expf(x) - 1.f; }

// ---- param LDS offsets (floats) ----
#define PB1 0
#define PG1 512
#define PBE1 1024
#define PB2 1536
#define PG2 1664
#define PBE2 1792
#define PB3 1920
#define PG3 1952
#define PBE3 1984
#define PB4 2016
#define PG4 2024
#define PBE4 2032
#define PW4 2040
#define PWH 2296
#define PBH 2304
#define PU  2305
#define NPAR 2306

// ws element offsets (u16), fragment-packed layouts:
// W1F: [ksg 0..32)[ntile 0..16)[lane 0..64)[e 0..8)   (n = ntile*32+(lane&31), k = ksg*16+(lane>>5)*8+e)
// W2F: [ksg 0..32)[ntile 0..4 )[lane][e]
// W3F/W3LF: [ksg 0..8)[lane][e]  (hi / lo-residual)
#define W1F_OFF 0
#define W2F_OFF 262144
#define W3F_OFF 327680
#define W3LF_OFF 331776
#define NGROUPS 41984     // total fragment groups of 8 elements

__global__ void prep_weights(const float* __restrict__ W1, const float* __restrict__ W2,
                             const float* __restrict__ W3, u16* __restrict__ wsb) {
    const int g = blockIdx.x * 256 + threadIdx.x;   // 164*256 == 41984 exactly
    if (g < 32768) {                                // W1 fragments
        const int l = g & 63, t = (g >> 6) & 15, ksg = g >> 10;
        const int n = t * 32 + (l & 31);
        const int k0 = ksg * 16 + (l >> 5) * 8;
        u16* dst = wsb + W1F_OFF + g * 8;
        const float* src = W1 + n * 512 + k0;
#pragma unroll
        for (int e = 0; e < 8; ++e) dst[e] = f2bf(src[e]);
    } else if (g < 40960) {                         // W2 fragments
        const int h = g - 32768;
        const int l = h & 63, t = (h >> 6) & 3, ksg = h >> 8;
        const int n = t * 32 + (l & 31);
        const int k0 = ksg * 16 + (l >> 5) * 8;
        u16* dst = wsb + W2F_OFF + h * 8;
        const float* src = W2 + n * 512 + k0;
#pragma unroll
        for (int e = 0; e < 8; ++e) dst[e] = f2bf(src[e]);
    } else if (g < 41472) {                         // W3 hi fragments
        const int h = g - 40960;
        const int l = h & 63, ksg = h >> 6;
        const int n = l & 31;
        const int k0 = ksg * 16 + (l >> 5) * 8;
        u16* dst = wsb + W3F_OFF + h * 8;
        const float* src = W3 + n * 128 + k0;
#pragma unroll
        for (int e = 0; e < 8; ++e) dst[e] = f2bf(src[e]);
    } else {                                        // W3 lo-residual fragments
        const int h = g - 41472;
        const int l = h & 63, ksg = h >> 6;
        const int n = l & 31;
        const int k0 = ksg * 16 + (l >> 5) * 8;
        u16* dst = wsb + W3LF_OFF + h * 8;
        const float* src = W3 + n * 128 + k0;
#pragma unroll
        for (int e = 0; e < 8; ++e) { float w = src[e]; dst[e] = f2bf(w - bfval(f2bf(w))); }
    }
}

__global__ __launch_bounds__(512, 2) void fused_mlp(
    const float* __restrict__ x,
    const u16* __restrict__ W1b, const u16* __restrict__ W2b,
    const u16* __restrict__ W3b, const u16* __restrict__ W3Lb,
    const float* __restrict__ b1, const float* __restrict__ g1, const float* __restrict__ be1,
    const float* __restrict__ b2, const float* __restrict__ g2, const float* __restrict__ be2,
    const float* __restrict__ b3, const float* __restrict__ g3, const float* __restrict__ be3,
    const float* __restrict__ W4, const float* __restrict__ b4, const float* __restrict__ g4,
    const float* __restrict__ be4,
    const float* __restrict__ Wh, const float* __restrict__ bh, const float* __restrict__ uvec,
    float* __restrict__ out, const int T)
{
    __shared__ __align__(16) u16 sXH[64][520];   // x-tile (bf16) then, in-place, h1 post-act
    __shared__ __align__(16) u16 sH2[64][136];   // h2 post-act bf16 hi
    __shared__ __align__(16) u16 sH2L[64][136];  // h2 post-act bf16 lo residual
    __shared__ __align__(16) float sH3f[64][36]; // h3 post-act fp32
    __shared__ __align__(16) float sPS[64][8];   // LN partial sums / reused as h4
    __shared__ __align__(16) float sPQ[64][8];   // LN partial sumsq
    __shared__ __align__(8)  float2 sMR[64];     // {mu, rsqrt}
    __shared__ __align__(16) float sP[NPAR + 2]; // staged params

    const int tid = threadIdx.x;
    const int wv = tid >> 6;          // wave 0..7
    const int lane = tid & 63;
    const int ln = lane & 31;
    const int lh = lane >> 5;
    const int Ng = wv;                // GEMM1: wave covers cols Ng*64..Ng*64+63, both M-tiles

    const long base = (long)blockIdx.x * T * 64 * 512;   // this block's x window (floats)

    // ---- tile-0 x prefetch into registers (16 coalesced float4 per thread) ----
    uint2 px[16];
    {
        const float4* xp = (const float4*)(x + base) + tid;
#pragma unroll
        for (int j = 0; j < 16; ++j) {
            float4 q = xp[j * 512];
            px[j] = make_uint2(pack2(q.x, q.y), pack2(q.z, q.w));
        }
    }

    // ---- stage small params into LDS (visible after first barrier) ----
    for (int i = tid; i < NPAR; i += 512) {
        float v;
        if      (i < 512)  v = b1[i];
        else if (i < 1024) v = g1[i - 512];
        else if (i < 1536) v = be1[i - 1024];
        else if (i < 1664) v = b2[i - 1536];
        else if (i < 1792) v = g2[i - 1664];
        else if (i < 1920) v = be2[i - 1792];
        else if (i < 1952) v = b3[i - 1920];
        else if (i < 1984) v = g3[i - 1952];
        else if (i < 2016) v = be3[i - 1984];
        else if (i < 2024) v = b4[i - 2016];
        else if (i < 2032) v = g4[i - 2024];
        else if (i < 2040) v = be4[i - 2032];
        else if (i < 2296) v = W4[i - 2040];
        else if (i < 2304) v = Wh[i - 2296];
        else if (i == 2304) v = bh[0];
        else                v = uvec[0];
        sP[i] = v;
    }

#pragma unroll 1
    for (int t = 0; t < T; ++t) {
        const long row0 = (long)blockIdx.x * T * 64 + (long)t * 64;

        // ---- phase0: dump register-prefetched x into sXH ----
        {
            const int r0 = tid >> 7;           // 0..3
            const int c4 = (tid & 127) * 4;    // 0..508
#pragma unroll
            for (int j = 0; j < 16; ++j)
                *(uint2*)(&sXH[j * 4 + r0][c4]) = px[j];
        }
        __syncthreads();                       // B1: x visible (also sP on t==0)

        // ================= GEMM1: h1 = x @ W1^T (M=64,N=512,K=512), barrier-free =================
        f32x16 acc[2][2] = {};                 // [mt][nt]
        {
            const u16* wq = W1b + (Ng * 2) * 512 + lane * 8;   // frag(ksg,nt) = wq + ksg*8192 + nt*512
            bf16x8 Bf[4][2];
#pragma unroll
            for (int s = 0; s < 3; ++s) {
                Bf[s][0] = *(const bf16x8*)(wq + s * 8192);
                Bf[s][1] = *(const bf16x8*)(wq + s * 8192 + 512);
            }
#pragma unroll
            for (int ksg = 0; ksg < 32; ++ksg) {
                const int slot = ksg & 3;
                if (ksg + 3 < 32) {
                    const int ps = (ksg + 3) & 3;
                    const u16* np = wq + (ksg + 3) * 8192;
                    Bf[ps][0] = *(const bf16x8*)(np);
                    Bf[ps][1] = *(const bf16x8*)(np + 512);
                }
                bf16x8 a0 = *(const bf16x8*)(&sXH[ln][ksg * 16 + lh * 8]);
                bf16x8 a1 = *(const bf16x8*)(&sXH[32 + ln][ksg * 16 + lh * 8]);
                acc[0][0] = __builtin_amdgcn_mfma_f32_32x32x16_bf16(a0, Bf[slot][0], acc[0][0], 0, 0, 0);
                acc[0][1] = __builtin_amdgcn_mfma_f32_32x32x16_bf16(a0, Bf[slot][1], acc[0][1], 0, 0, 0);
                acc[1][0] = __builtin_amdgcn_mfma_f32_32x32x16_bf16(a1, Bf[slot][0], acc[1][0], 0, 0, 0);
                acc[1][1] = __builtin_amdgcn_mfma_f32_32x32x16_bf16(a1, Bf[slot][1], acc[1][1], 0, 0, 0);
            }
        }

        // ---- issue x prefetch for tile t+1 (after all W1 loads -> no vmcnt coupling) ----
        if (t + 1 < T) {
            const float4* xp = (const float4*)(x + base + (long)(t + 1) * 64 * 512) + tid;
#pragma unroll
            for (int j = 0; j < 16; ++j) {
                float4 q = xp[j * 512];
                px[j] = make_uint2(pack2(q.x, q.y), pack2(q.z, q.w));
            }
        }

        // ---- LN1: fold bias, in-register butterfly row sums ----
        {
            const float b0 = sP[PB1 + Ng * 64 + ln];
            const float b1c = sP[PB1 + Ng * 64 + 32 + ln];
#pragma unroll
            for (int rg = 0; rg < 16; ++rg) {
                acc[0][0][rg] += b0; acc[0][1][rg] += b1c;
                acc[1][0][rg] += b0; acc[1][1][rg] += b1c;
            }
        }
#pragma unroll
        for (int mt = 0; mt < 2; ++mt)
#pragma unroll
        for (int rg = 0; rg < 16; ++rg) {
            float s = acc[mt][0][rg] + acc[mt][1][rg];
            float q = acc[mt][0][rg] * acc[mt][0][rg] + acc[mt][1][rg] * acc[mt][1][rg];
#pragma unroll
            for (int m = 1; m < 32; m <<= 1) { s += __shfl_xor(s, m, 64); q += __shfl_xor(q, m, 64); }
            if (ln == 0) {
                const int row = mt * 32 + (rg & 3) + 8 * (rg >> 2) + 4 * lh;
                sPS[row][Ng] = s; sPQ[row][Ng] = q;
            }
        }
        __syncthreads();                       // B2
        if (tid < 64) {
            float s = 0.f, q = 0.f;
#pragma unroll
            for (int j = 0; j < 8; ++j) { s += sPS[tid][j]; q += sPQ[tid][j]; }
            const float mu = s * (1.f / 512.f);
            const float var = q * (1.f / 512.f) - mu * mu;
            sMR[tid] = make_float2(mu, rsqrtf(var + 1e-5f));
        }
        __syncthreads();                       // B3
        // ---- LN1 apply + CELU -> overwrite sXH with h1 (x dead) ----
        {
            const float g0 = sP[PG1 + Ng * 64 + ln];
            const float gA = sP[PG1 + Ng * 64 + 32 + ln];
            const float e0 = sP[PBE1 + Ng * 64 + ln];
            const float eA = sP[PBE1 + Ng * 64 + 32 + ln];
#pragma unroll
            for (int mt = 0; mt < 2; ++mt)
#pragma unroll
            for (int rg = 0; rg < 16; ++rg) {
                const int row = mt * 32 + (rg & 3) + 8 * (rg >> 2) + 4 * lh;
                const float2 mr = sMR[row];
                const float h0 = (acc[mt][0][rg] - mr.x) * mr.y * g0 + e0;
                const float h1v = (acc[mt][1][rg] - mr.x) * mr.y * gA + eA;
                sXH[row][Ng * 64 + ln] = f2bf(celu1(h0));
                sXH[row][Ng * 64 + 32 + ln] = f2bf(celu1(h1v));
            }
        }
        __syncthreads();                       // B4: h1 visible

        // ================= GEMM2: h2 = h1 @ W2^T (M=64,N=128,K=512) =================
        float v2[16];
        {
            const int Mt2 = wv >> 2;
            const int Nt2 = wv & 3;
            const u16* w2q = W2b + Nt2 * 512 + lane * 8;   // frag(ksg) = w2q + ksg*2048
            bf16x8 W2f[4];
#pragma unroll
            for (int s = 0; s < 4; ++s) W2f[s] = *(const bf16x8*)(w2q + s * 2048);
            f32x16 a2 = {}, a2b = {};
            const u16* h1p = &sXH[Mt2 * 32 + ln][lh * 8];
#pragma unroll
            for (int ksg = 0; ksg < 32; ++ksg) {
                const int slot = ksg & 3;
                bf16x8 af = *(const bf16x8*)(h1p + ksg * 16);
                if (ksg & 1) a2b = __builtin_amdgcn_mfma_f32_32x32x16_bf16(af, W2f[slot], a2b, 0, 0, 0);
                else         a2  = __builtin_amdgcn_mfma_f32_32x32x16_bf16(af, W2f[slot], a2, 0, 0, 0);
                if (ksg + 4 < 32) W2f[slot] = *(const bf16x8*)(w2q + (ksg + 4) * 2048);
            }
            const float bb = sP[PB2 + Nt2 * 32 + ln];
#pragma unroll
            for (int rg = 0; rg < 16; ++rg) v2[rg] = a2[rg] + a2b[rg] + bb;
#pragma unroll
            for (int rg = 0; rg < 16; ++rg) {
                float s = v2[rg], q = v2[rg] * v2[rg];
#pragma unroll
                for (int m = 1; m < 32; m <<= 1) { s += __shfl_xor(s, m, 64); q += __shfl_xor(q, m, 64); }
                if (ln == 0) {
                    const int row = Mt2 * 32 + (rg & 3) + 8 * (rg >> 2) + 4 * lh;
                    sPS[row][Nt2] = s; sPQ[row][Nt2] = q;
                }
            }
        }
        __syncthreads();                       // B5
        if (tid < 64) {
            float s = sPS[tid][0] + sPS[tid][1] + sPS[tid][2] + sPS[tid][3];
            float q = sPQ[tid][0] + sPQ[tid][1] + sPQ[tid][2] + sPQ[tid][3];
            const float mu = s * (1.f / 128.f);
            const float var = q * (1.f / 128.f) - mu * mu;
            sMR[tid] = make_float2(mu, rsqrtf(var + 1e-5f));
        }
        __syncthreads();                       // B6
        {
            const int Mt2 = wv >> 2;
            const int Nt2 = wv & 3;
            const int col = Nt2 * 32 + ln;
            const float gg = sP[PG2 + col], ee = sP[PBE2 + col];
#pragma unroll
            for (int rg = 0; rg < 16; ++rg) {
                const int row = Mt2 * 32 + (rg & 3) + 8 * (rg >> 2) + 4 * lh;
                const float2 mr = sMR[row];
                const float hn = (v2[rg] - mr.x) * mr.y * gg + ee;
                const float a = celu1(hn);
                const u16 hi = f2bf(a);
                sH2[row][col] = hi;
                sH2L[row][col] = f2bf(a - bfval(hi));
            }
        }
        __syncthreads();                       // B7

        // ===== GEMM3: h3 = h2 @ W3^T (M=64,N=32,K=128), split-precision, waves 0-1 =====
        if (wv < 2) {
            f32x16 a3 = {};
            const u16* w3q  = W3b  + lane * 8;
            const u16* w3lq = W3Lb + lane * 8;
            const u16* h2p  = &sH2 [wv * 32 + ln][lh * 8];
            const u16* h2lp = &sH2L[wv * 32 + ln][lh * 8];
#pragma unroll
            for (int ks = 0; ks < 8; ++ks) {
                bf16x8 fa_h = *(const bf16x8*)(h2p  + ks * 16);
                bf16x8 fa_l = *(const bf16x8*)(h2lp + ks * 16);
                bf16x8 fb_h = *(const bf16x8*)(w3q  + ks * 512);
                bf16x8 fb_l = *(const bf16x8*)(w3lq + ks * 512);
                a3 = __builtin_amdgcn_mfma_f32_32x32x16_bf16(fa_h, fb_h, a3, 0, 0, 0);
                a3 = __builtin_amdgcn_mfma_f32_32x32x16_bf16(fa_h, fb_l, a3, 0, 0, 0);
                a3 = __builtin_amdgcn_mfma_f32_32x32x16_bf16(fa_l, fb_h, a3, 0, 0, 0);
            }
            const float bb = sP[PB3 + ln];
            const float g3v = sP[PG3 + ln], e3v = sP[PBE3 + ln];
#pragma unroll
            for (int rg = 0; rg < 16; ++rg) {
                const float v = a3[rg] + bb;
                float s = v, q = v * v;
#pragma unroll
                for (int m = 1; m < 32; m <<= 1) { s += __shfl_xor(s, m, 64); q += __shfl_xor(q, m, 64); }
                const float mu = s * (1.f / 32.f);
                const float rs = rsqrtf(q * (1.f / 32.f) - mu * mu + 1e-5f);
                const int row = wv * 32 + (rg & 3) + 8 * (rg >> 2) + 4 * lh;
                sH3f[row][ln] = celu1((v - mu) * rs * g3v + e3v);
            }
        }
        __syncthreads();                       // B8

        // ================= Layer4 (fp32): h4 = h3 @ W4^T + b4 (width 8) =================
        if (tid < 256) {
            const int r = tid & 63, og = tid >> 6;
            float h[32];
            const float4* hp = (const float4*)(&sH3f[r][0]);
#pragma unroll
            for (int j = 0; j < 8; ++j) {
                float4 tv = hp[j];
                h[j * 4 + 0] = tv.x; h[j * 4 + 1] = tv.y; h[j * 4 + 2] = tv.z; h[j * 4 + 3] = tv.w;
            }
#pragma unroll
            for (int oo = 0; oo < 2; ++oo) {
                const int o = og * 2 + oo;
                float a = sP[PB4 + o];
                const float* w4 = &sP[PW4 + o * 32];
#pragma unroll
                for (int k = 0; k < 32; ++k) a += h[k] * w4[k];
                sPS[r][o] = a;
            }
        }
        __syncthreads();                       // B9

        // ================= LN4 + CELU + spectral-norm head =================
        if (tid < 64) {
            float v[8];
            float s = 0.f, q = 0.f;
#pragma unroll
            for (int o = 0; o < 8; ++o) { v[o] = sPS[tid][o]; s += v[o]; q += v[o] * v[o]; }
            const float mu = s * 0.125f;
            const float var = q * 0.125f - mu * mu;
            const float rs = rsqrtf(var + 1e-5f);

            float wh[8];
            const float u0 = sP[PU];
            float nv = 0.f;
#pragma unroll
            for (int o = 0; o < 8; ++o) { wh[o] = sP[PWH + o]; float tt = wh[o] * u0; nv += tt * tt; }
            nv = sqrtf(nv);
            const float inv = 1.f / (nv + 1e-12f);
            float s2 = 0.f;
#pragma unroll
            for (int o = 0; o < 8; ++o) s2 += wh[o] * (wh[o] * u0 * inv);
            const float u2 = s2 / (fabsf(s2) + 1e-12f);
            const float sigma = u2 * s2;
            const float isg = 1.f / sigma;

            float y = sP[PBH];
#pragma unroll
            for (int o = 0; o < 8; ++o) {
                const float hn = (v[o] - mu) * rs * sP[PG4 + o] + sP[PBE4 + o];
                y += celu1(hn) * wh[o] * isg;
            }
            out[row0 + tid] = y;
        }
        // next-tile phase0 write targets sXH (h1 dead after GEMM2); sPS reuse is
        // protected by B2 of the next iteration.
    }
}

extern "C" void kernel_launch(void* const* d_in, const int* in_sizes, int n_in,
                              void* d_out, int out_size, void* d_ws, size_t ws_size,
                              hipStream_t stream) {
    const float* x   = (const float*)d_in[0];
    const float* W1  = (const float*)d_in[1];
    const float* b1  = (const float*)d_in[2];
    const float* g1  = (const float*)d_in[3];
    const float* be1 = (const float*)d_in[4];
    const float* W2  = (const float*)d_in[5];
    const float* b2  = (const float*)d_in[6];
    const float* g2  = (const float*)d_in[7];
    const float* be2 = (const float*)d_in[8];
    const float* W3  = (const float*)d_in[9];
    const float* b3  = (const float*)d_in[10];
    const float* g3  = (const float*)d_in[11];
    const float* be3 = (const float*)d_in[12];
    const float* W4  = (const float*)d_in[13];
    const float* b4  = (const float*)d_in[14];
    const float* g4  = (const float*)d_in[15];
    const float* be4 = (const float*)d_in[16];
    const float* Wh  = (const float*)d_in[17];
    const float* bh  = (const float*)d_in[18];
    const float* u   = (const float*)d_in[19];
    float* out = (float*)d_out;
    u16* wsb = (u16*)d_ws;

    prep_weights<<<dim3(NGROUPS / 256), dim3(256), 0, stream>>>(W1, W2, W3, wsb);

    const int rows = in_sizes[0] / 512;       // 131072
    const int blocks = 256;                   // persistent: 1 per CU (LDS-limited)
    const int T = rows / 64 / blocks;         // 8 tiles per block
    fused_mlp<<<dim3(blocks), dim3(512), 0, stream>>>(
        x, wsb + W1F_OFF, wsb + W2F_OFF, wsb + W3F_OFF, wsb + W3LF_OFF,
        b1, g1, be1, b2, g2, be2, b3, g3, be3,
        W4, b4, g4, be4, Wh, bh, u, out, T);
}

// Round 5
// 545.166 us; speedup vs baseline: 1.4639x; 1.4639x over previous
//
#include <hip/hip_runtime.h>

// Fused MLP: x[131072,512] -> (Linear+LN+CELU)x4 -> spectral-norm head -> [131072,1]
// R5: occupancy fix. 2048 blocks x 512 thr, one 64-row tile per block, LDS cut to
// ~72KB so 2 blocks/CU co-reside (16 waves/CU) and overlap each other's barrier/LN
// phases. Single sXH buffer reused in place: x -> h1 -> {h2hi, h2lo, h3f} at
// disjoint offsets. Per-wave LN params live in registers (no big sP). No register
// prefetch held across barriers (R4's spill bug). Weights pre-packed in MFMA
// fragment order (coalesced 1KB bursts). GEMM1/2 bf16 MFMA + in-register fp32
// LayerNorm; GEMM3 split-precision bf16; layer4+head fp32.

typedef unsigned short u16;
typedef unsigned int   u32;
typedef __bf16  bf16x8 __attribute__((ext_vector_type(8)));
typedef float   f32x16 __attribute__((ext_vector_type(16)));

__device__ __forceinline__ u16 f2bf(float f) {           // RTN-even f32->bf16
    u32 x = __builtin_bit_cast(u32, f);
    x += 0x7FFFu + ((x >> 16) & 1u);
    return (u16)(x >> 16);
}
__device__ __forceinline__ float bfval(u16 h) { return __builtin_bit_cast(float, (u32)h << 16); }
__device__ __forceinline__ u32 pack2(float a, float b) { return (u32)f2bf(a) | ((u32)f2bf(b) << 16); }
__device__ __forceinline__ float celu1(float x) { return x > 0.f ? x : __expf(x) - 1.f; }

// ws element offsets (u16), fragment-packed layouts:
// W1F: [ksg 0..32)[ntile 0..16)[lane 0..64)[e 0..8)
// W2F: [ksg 0..32)[ntile 0..4 )[lane][e]
// W3F/W3LF: [ksg 0..8)[lane][e]  (hi / lo-residual)
#define W1F_OFF 0
#define W2F_OFF 262144
#define W3F_OFF 327680
#define W3LF_OFF 331776
#define NGROUPS 41984

__global__ void prep_weights(const float* __restrict__ W1, const float* __restrict__ W2,
                             const float* __restrict__ W3, u16* __restrict__ wsb) {
    const int g = blockIdx.x * 256 + threadIdx.x;   // 164*256 == 41984 exactly
    if (g < 32768) {                                // W1 fragments
        const int l = g & 63, t = (g >> 6) & 15, ksg = g >> 10;
        const int n = t * 32 + (l & 31);
        const int k0 = ksg * 16 + (l >> 5) * 8;
        u16* dst = wsb + W1F_OFF + g * 8;
        const float* src = W1 + n * 512 + k0;
#pragma unroll
        for (int e = 0; e < 8; ++e) dst[e] = f2bf(src[e]);
    } else if (g < 40960) {                         // W2 fragments
        const int h = g - 32768;
        const int l = h & 63, t = (h >> 6) & 3, ksg = h >> 8;
        const int n = t * 32 + (l & 31);
        const int k0 = ksg * 16 + (l >> 5) * 8;
        u16* dst = wsb + W2F_OFF + h * 8;
        const float* src = W2 + n * 512 + k0;
#pragma unroll
        for (int e = 0; e < 8; ++e) dst[e] = f2bf(src[e]);
    } else if (g < 41472) {                         // W3 hi fragments
        const int h = g - 40960;
        const int l = h & 63, ksg = h >> 6;
        const int n = l & 31;
        const int k0 = ksg * 16 + (l >> 5) * 8;
        u16* dst = wsb + W3F_OFF + h * 8;
        const float* src = W3 + n * 128 + k0;
#pragma unroll
        for (int e = 0; e < 8; ++e) dst[e] = f2bf(src[e]);
    } else {                                        // W3 lo-residual fragments
        const int h = g - 41472;
        const int l = h & 63, ksg = h >> 6;
        const int n = l & 31;
        const int k0 = ksg * 16 + (l >> 5) * 8;
        u16* dst = wsb + W3LF_OFF + h * 8;
        const float* src = W3 + n * 128 + k0;
#pragma unroll
        for (int e = 0; e < 8; ++e) { float w = src[e]; dst[e] = f2bf(w - bfval(f2bf(w))); }
    }
}

// head-param LDS layout (floats)
#define PW4 0
#define PB4 256
#define PG4 264
#define PBE4 272
#define PWH 280
#define PBH 288
#define PU  289
#define NPAR 290

__global__ __launch_bounds__(512, 4) void fused_mlp(
    const float* __restrict__ x,
    const u16* __restrict__ W1b, const u16* __restrict__ W2b,
    const u16* __restrict__ W3b, const u16* __restrict__ W3Lb,
    const float* __restrict__ b1, const float* __restrict__ g1, const float* __restrict__ be1,
    const float* __restrict__ b2, const float* __restrict__ g2, const float* __restrict__ be2,
    const float* __restrict__ b3, const float* __restrict__ g3, const float* __restrict__ be3,
    const float* __restrict__ W4, const float* __restrict__ b4, const float* __restrict__ g4,
    const float* __restrict__ be4,
    const float* __restrict__ Wh, const float* __restrict__ bh, const float* __restrict__ uvec,
    float* __restrict__ out)
{
    // Single big buffer, reused in place:
    //   phase GEMM1 : u16 cols [0,512)  = x tile (bf16)
    //   after LN1   : u16 cols [0,512)  = h1 post-act (bf16)
    //   after LN2   : u16 cols [0,128)  = h2 hi, [128,256) = h2 lo
    //   after GEMM3 : f32 cols [256/2..] i.e. u16 cols [512..584) = h3f (32 floats)
    __shared__ __align__(16) u16 sXH[64][520];
    __shared__ __align__(16) float sPS[64][8];   // LN partials / h4
    __shared__ __align__(16) float sPQ[64][8];
    __shared__ __align__(8)  float2 sMR[64];     // {mu, rsqrt}
    __shared__ __align__(16) float sP[NPAR + 2]; // head params

    const int tid = threadIdx.x;
    const int wv = tid >> 6;          // wave 0..7
    const int lane = tid & 63;
    const int ln = lane & 31;
    const int lh = lane >> 5;
    const int Ng = wv;                // GEMM1: wave covers cols Ng*64..Ng*64+63
    const int row0 = blockIdx.x * 64;

    // ---- per-wave LN/bias params in registers (tiny, L2-hot) ----
    const float b1a = b1[Ng * 64 + ln],  b1c = b1[Ng * 64 + 32 + ln];
    const float g1a = g1[Ng * 64 + ln],  g1c = g1[Ng * 64 + 32 + ln];
    const float e1a = be1[Ng * 64 + ln], e1c = be1[Ng * 64 + 32 + ln];
    const int Mt2 = wv >> 2, Nt2 = wv & 3;
    const float b2v = b2[Nt2 * 32 + ln], g2v = g2[Nt2 * 32 + ln], e2v = be2[Nt2 * 32 + ln];
    const float b3v = b3[ln], g3v = g3[ln], e3v = be3[ln];

    // ---- stage head params ----
    if (tid < NPAR) {
        float v;
        if      (tid < 256) v = W4[tid];
        else if (tid < 264) v = b4[tid - 256];
        else if (tid < 272) v = g4[tid - 264];
        else if (tid < 280) v = be4[tid - 272];
        else if (tid < 288) v = Wh[tid - 280];
        else if (tid == 288) v = bh[0];
        else                v = uvec[0];
        sP[tid] = v;
    }

    // ---- phase0: stage whole x tile as bf16 (transient registers only) ----
    {
        const float4* xp = (const float4*)(x) + (long)blockIdx.x * 8192 + tid;
        float4 q[16];
#pragma unroll
        for (int j = 0; j < 16; ++j) q[j] = xp[j * 512];
        const int r0 = tid >> 7;           // 0..3
        const int c4 = (tid & 127) * 4;    // u16 col 0..508
#pragma unroll
        for (int j = 0; j < 16; ++j)
            *(uint2*)(&sXH[j * 4 + r0][c4]) =
                make_uint2(pack2(q[j].x, q[j].y), pack2(q[j].z, q[j].w));
    }
    __syncthreads();                       // B1: x + sP visible

    // ================= GEMM1: h1 = x @ W1^T (M=64,N=512,K=512), barrier-free =================
    f32x16 acc[2][2] = {};                 // [mt][nt]
    {
        const u16* wq = W1b + (Ng * 2) * 512 + lane * 8;   // frag(ksg,nt) = wq + ksg*8192 + nt*512
        bf16x8 Bf[4][2];
#pragma unroll
        for (int s = 0; s < 3; ++s) {
            Bf[s][0] = *(const bf16x8*)(wq + s * 8192);
            Bf[s][1] = *(const bf16x8*)(wq + s * 8192 + 512);
        }
#pragma unroll
        for (int ksg = 0; ksg < 32; ++ksg) {
            const int slot = ksg & 3;
            if (ksg + 3 < 32) {
                const int ps = (ksg + 3) & 3;
                const u16* np = wq + (ksg + 3) * 8192;
                Bf[ps][0] = *(const bf16x8*)(np);
                Bf[ps][1] = *(const bf16x8*)(np + 512);
            }
            bf16x8 a0 = *(const bf16x8*)(&sXH[ln][ksg * 16 + lh * 8]);
            bf16x8 a1 = *(const bf16x8*)(&sXH[32 + ln][ksg * 16 + lh * 8]);
            acc[0][0] = __builtin_amdgcn_mfma_f32_32x32x16_bf16(a0, Bf[slot][0], acc[0][0], 0, 0, 0);
            acc[0][1] = __builtin_amdgcn_mfma_f32_32x32x16_bf16(a0, Bf[slot][1], acc[0][1], 0, 0, 0);
            acc[1][0] = __builtin_amdgcn_mfma_f32_32x32x16_bf16(a1, Bf[slot][0], acc[1][0], 0, 0, 0);
            acc[1][1] = __builtin_amdgcn_mfma_f32_32x32x16_bf16(a1, Bf[slot][1], acc[1][1], 0, 0, 0);
        }
    }

    // ---- LN1: fold bias, in-register butterfly row sums ----
#pragma unroll
    for (int rg = 0; rg < 16; ++rg) {
        acc[0][0][rg] += b1a; acc[0][1][rg] += b1c;
        acc[1][0][rg] += b1a; acc[1][1][rg] += b1c;
    }
#pragma unroll
    for (int mt = 0; mt < 2; ++mt)
#pragma unroll
    for (int rg = 0; rg < 16; ++rg) {
        float s = acc[mt][0][rg] + acc[mt][1][rg];
        float q = acc[mt][0][rg] * acc[mt][0][rg] + acc[mt][1][rg] * acc[mt][1][rg];
#pragma unroll
        for (int m = 1; m < 32; m <<= 1) { s += __shfl_xor(s, m, 64); q += __shfl_xor(q, m, 64); }
        if (ln == 0) {
            const int row = mt * 32 + (rg & 3) + 8 * (rg >> 2) + 4 * lh;
            sPS[row][Ng] = s; sPQ[row][Ng] = q;
        }
    }
    __syncthreads();                       // B2
    if (tid < 64) {
        float s = 0.f, q = 0.f;
#pragma unroll
        for (int j = 0; j < 8; ++j) { s += sPS[tid][j]; q += sPQ[tid][j]; }
        const float mu = s * (1.f / 512.f);
        const float var = q * (1.f / 512.f) - mu * mu;
        sMR[tid] = make_float2(mu, rsqrtf(var + 1e-5f));
    }
    __syncthreads();                       // B3
    // ---- LN1 apply + CELU -> overwrite sXH with h1 (x dead) ----
#pragma unroll
    for (int mt = 0; mt < 2; ++mt)
#pragma unroll
    for (int rg = 0; rg < 16; ++rg) {
        const int row = mt * 32 + (rg & 3) + 8 * (rg >> 2) + 4 * lh;
        const float2 mr = sMR[row];
        const float h0 = (acc[mt][0][rg] - mr.x) * mr.y * g1a + e1a;
        const float h1v = (acc[mt][1][rg] - mr.x) * mr.y * g1c + e1c;
        sXH[row][Ng * 64 + ln] = f2bf(celu1(h0));
        sXH[row][Ng * 64 + 32 + ln] = f2bf(celu1(h1v));
    }
    __syncthreads();                       // B4: h1 visible

    // ================= GEMM2: h2 = h1 @ W2^T (M=64,N=128,K=512) =================
    float v2[16];
    {
        const u16* w2q = W2b + Nt2 * 512 + lane * 8;   // frag(ksg) = w2q + ksg*2048
        bf16x8 W2f[4];
#pragma unroll
        for (int s = 0; s < 4; ++s) W2f[s] = *(const bf16x8*)(w2q + s * 2048);
        f32x16 a2 = {}, a2b = {};
        const u16* h1p = &sXH[Mt2 * 32 + ln][lh * 8];
#pragma unroll
        for (int ksg = 0; ksg < 32; ++ksg) {
            const int slot = ksg & 3;
            bf16x8 af = *(const bf16x8*)(h1p + ksg * 16);
            if (ksg & 1) a2b = __builtin_amdgcn_mfma_f32_32x32x16_bf16(af, W2f[slot], a2b, 0, 0, 0);
            else         a2  = __builtin_amdgcn_mfma_f32_32x32x16_bf16(af, W2f[slot], a2, 0, 0, 0);
            if (ksg + 4 < 32) W2f[slot] = *(const bf16x8*)(w2q + (ksg + 4) * 2048);
        }
#pragma unroll
        for (int rg = 0; rg < 16; ++rg) v2[rg] = a2[rg] + a2b[rg] + b2v;
#pragma unroll
        for (int rg = 0; rg < 16; ++rg) {
            float s = v2[rg], q = v2[rg] * v2[rg];
#pragma unroll
            for (int m = 1; m < 32; m <<= 1) { s += __shfl_xor(s, m, 64); q += __shfl_xor(q, m, 64); }
            if (ln == 0) {
                const int row = Mt2 * 32 + (rg & 3) + 8 * (rg >> 2) + 4 * lh;
                sPS[row][Nt2] = s; sPQ[row][Nt2] = q;
            }
        }
    }
    __syncthreads();                       // B5
    if (tid < 64) {
        float s = sPS[tid][0] + sPS[tid][1] + sPS[tid][2] + sPS[tid][3];
        float q = sPQ[tid][0] + sPQ[tid][1] + sPQ[tid][2] + sPQ[tid][3];
        const float mu = s * (1.f / 128.f);
        const float var = q * (1.f / 128.f) - mu * mu;
        sMR[tid] = make_float2(mu, rsqrtf(var + 1e-5f));
    }
    __syncthreads();                       // B6
    // ---- LN2 apply + CELU -> h2 hi/lo into sXH cols [0,128)+[128,256) (h1 dead) ----
    {
        const int col = Nt2 * 32 + ln;
#pragma unroll
        for (int rg = 0; rg < 16; ++rg) {
            const int row = Mt2 * 32 + (rg & 3) + 8 * (rg >> 2) + 4 * lh;
            const float2 mr = sMR[row];
            const float hn = (v2[rg] - mr.x) * mr.y * g2v + e2v;
            const float a = celu1(hn);
            const u16 hi = f2bf(a);
            sXH[row][col] = hi;
            sXH[row][128 + col] = f2bf(a - bfval(hi));
        }
    }
    __syncthreads();                       // B7

    // ===== GEMM3: h3 = h2 @ W3^T (M=64,N=32,K=128), split-precision, waves 0-1 =====
    if (wv < 2) {
        f32x16 a3 = {};
        const u16* w3q  = W3b  + lane * 8;
        const u16* w3lq = W3Lb + lane * 8;
        const u16* h2p  = &sXH[wv * 32 + ln][lh * 8];
        const u16* h2lp = &sXH[wv * 32 + ln][128 + lh * 8];
#pragma unroll
        for (int ks = 0; ks < 8; ++ks) {
            bf16x8 fa_h = *(const bf16x8*)(h2p  + ks * 16);
            bf16x8 fa_l = *(const bf16x8*)(h2lp + ks * 16);
            bf16x8 fb_h = *(const bf16x8*)(w3q  + ks * 512);
            bf16x8 fb_l = *(const bf16x8*)(w3lq + ks * 512);
            a3 = __builtin_amdgcn_mfma_f32_32x32x16_bf16(fa_h, fb_h, a3, 0, 0, 0);
            a3 = __builtin_amdgcn_mfma_f32_32x32x16_bf16(fa_h, fb_l, a3, 0, 0, 0);
            a3 = __builtin_amdgcn_mfma_f32_32x32x16_bf16(fa_l, fb_h, a3, 0, 0, 0);
        }
        // LN3 fully in-register (width 32 == ln-group) -> fp32 h3 at u16 cols [512,576)
#pragma unroll
        for (int rg = 0; rg < 16; ++rg) {
            const float v = a3[rg] + b3v;
            float s = v, q = v * v;
#pragma unroll
            for (int m = 1; m < 32; m <<= 1) { s += __shfl_xor(s, m, 64); q += __shfl_xor(q, m, 64); }
            const float mu = s * (1.f / 32.f);
            const float rs = rsqrtf(q * (1.f / 32.f) - mu * mu + 1e-5f);
            const int row = wv * 32 + (rg & 3) + 8 * (rg >> 2) + 4 * lh;
            float* s3 = (float*)&sXH[row][256 * 2];   // byte offset 1024? no: col 512 u16 = byte 1024 > row! 
            s3 = (float*)&sXH[row][0] + 128;          // f32 idx 128 = u16 col 256?  -- see note below
            // NOTE: h2 occupies u16 cols [0,256) = f32 idx [0,128). Place h3f at f32 idx [128,160)
            //       = u16 cols [256,320), safely inside the 520-col row and disjoint from h2.
            s3[ln] = celu1((v - mu) * rs * g3v + e3v);
        }
    }
    __syncthreads();                       // B8

    // ================= Layer4 (fp32): h4 = h3 @ W4^T + b4 (width 8) =================
    if (tid < 256) {
        const int r = tid & 63, og = tid >> 6;
        float h[32];
        const float4* hp = (const float4*)((float*)&sXH[r][0] + 128);
#pragma unroll
        for (int j = 0; j < 8; ++j) {
            float4 tv = hp[j];
            h[j * 4 + 0] = tv.x; h[j * 4 + 1] = tv.y; h[j * 4 + 2] = tv.z; h[j * 4 + 3] = tv.w;
        }
#pragma unroll
        for (int oo = 0; oo < 2; ++oo) {
            const int o = og * 2 + oo;
            float a = sP[PB4 + o];
            const float* w4 = &sP[PW4 + o * 32];
#pragma unroll
            for (int k = 0; k < 32; ++k) a += h[k] * w4[k];
            sPS[r][o] = a;
        }
    }
    __syncthreads();                       // B9

    // ================= LN4 + CELU + spectral-norm head =================
    if (tid < 64) {
        float v[8];
        float s = 0.f, q = 0.f;
#pragma unroll
        for (int o = 0; o < 8; ++o) { v[o] = sPS[tid][o]; s += v[o]; q += v[o] * v[o]; }
        const float mu = s * 0.125f;
        const float var = q * 0.125f - mu * mu;
        const float rs = rsqrtf(var + 1e-5f);

        float wh[8];
        const float u0 = sP[PU];
        float nv = 0.f;
#pragma unroll
        for (int o = 0; o < 8; ++o) { wh[o] = sP[PWH + o]; float tt = wh[o] * u0; nv += tt * tt; }
        nv = sqrtf(nv);
        const float inv = 1.f / (nv + 1e-12f);
        float s2 = 0.f;
#pragma unroll
        for (int o = 0; o < 8; ++o) s2 += wh[o] * (wh[o] * u0 * inv);
        const float u2 = s2 / (fabsf(s2) + 1e-12f);
        const float sigma = u2 * s2;
        const float isg = 1.f / sigma;

        float y = sP[PBH];
#pragma unroll
        for (int o = 0; o < 8; ++o) {
            const float hn = (v[o] - mu) * rs * sP[PG4 + o] + sP[PBE4 + o];
            y += celu1(hn) * wh[o] * isg;
        }
        out[row0 + tid] = y;
    }
}

extern "C" void kernel_launch(void* const* d_in, const int* in_sizes, int n_in,
                              void* d_out, int out_size, void* d_ws, size_t ws_size,
                              hipStream_t stream) {
    const float* x   = (const float*)d_in[0];
    const float* W1  = (const float*)d_in[1];
    const float* b1  = (const float*)d_in[2];
    const float* g1  = (const float*)d_in[3];
    const float* be1 = (const float*)d_in[4];
    const float* W2  = (const float*)d_in[5];
    const float* b2  = (const float*)d_in[6];
    const float* g2  = (const float*)d_in[7];
    const float* be2 = (const float*)d_in[8];
    const float* W3  = (const float*)d_in[9];
    const float* b3  = (const float*)d_in[10];
    const float* g3  = (const float*)d_in[11];
    const float* be3 = (const float*)d_in[12];
    const float* W4  = (const float*)d_in[13];
    const float* b4  = (const float*)d_in[14];
    const float* g4  = (const float*)d_in[15];
    const float* be4 = (const float*)d_in[16];
    const float* Wh  = (const float*)d_in[17];
    const float* bh  = (const float*)d_in[18];
    const float* u   = (const float*)d_in[19];
    float* out = (float*)d_out;
    u16* wsb = (u16*)d_ws;

    prep_weights<<<dim3(NGROUPS / 256), dim3(256), 0, stream>>>(W1, W2, W3, wsb);

    const int rows = in_sizes[0] / 512;       // 131072
    fused_mlp<<<dim3(rows / 64), dim3(512), 0, stream>>>(
        x, wsb + W1F_OFF, wsb + W2F_OFF, wsb + W3F_OFF, wsb + W3LF_OFF,
        b1, g1, be1, b2, g2, be2, b3, g3, be3,
        W4, b4, g4, be4, Wh, bh, u, out);
}